// Round 9
// baseline (219.839 us; speedup 1.0000x reference)
//
#include <hip/hip_runtime.h>
#include <hip/hip_fp16.h>
#include <math.h>

#define N_NODES 100000
#define N_EDGES 1600000
#define IN_DIM  128
#define HID     64
#define NCOMM   32
#define NB        391   // ceil(100000/256) coarse buckets
#define BSHIFT    8     // 256 nodes per bucket
#define BCAP      6144  // fixed bucket capacity: mean 4096 + 32 sigma (binomial sd=64)
#define EPB       4096  // edges per block in binning kernel
#define NBIN_BLK  391   // ceil(1600000/4096)

typedef _Float16 f16x8 __attribute__((ext_vector_type(8)));
typedef float    f32x4 __attribute__((ext_vector_type(4)));

// ---------- edge dtype detection (int64 vs int32), parallel, deterministic ----------
__global__ void k_detect(const unsigned int* __restrict__ e, int* __restrict__ flag) {
  int lane = threadIdx.x;  // 64 lanes
  unsigned v = 0;
  #pragma unroll
  for (int i = 0; i < 4; ++i) v |= e[2 * (lane * 4 + i) + 1];
  unsigned long long nz = __ballot(v != 0u);
  if (lane == 0) *flag = (nz == 0ull) ? 1 : 0;  // 1 => int64 layout
}

__device__ __forceinline__ int load_idx(const int* e32, long long pos, int is64) {
  if (is64) return (int)(((const long long*)e32)[pos]);
  return e32[pos];
}

// ---------- bin edges into fixed-capacity buckets, packed: bits[0:17)=r, bits[17:25)=c&255 ----------
__global__ __launch_bounds__(256) void k_bin(const int* __restrict__ e, int* __restrict__ bcnt,
                                             unsigned* __restrict__ ebuf, const int* __restrict__ flag) {
  __shared__ int cnt[NB];
  __shared__ int base[NB];
  for (int i = threadIdx.x; i < NB; i += 256) cnt[i] = 0;
  __syncthreads();
  int is64 = *flag;
  long long eb = (long long)blockIdx.x * EPB;
  int rr[EPB / 256], cc[EPB / 256], lr[EPB / 256];
  #pragma unroll
  for (int j = 0; j < EPB / 256; ++j) {
    long long eid = eb + j * 256 + threadIdx.x;
    if (eid < N_EDGES) {
      rr[j] = load_idx(e, eid, is64);
      cc[j] = load_idx(e, (long long)N_EDGES + eid, is64);
      lr[j] = atomicAdd(&cnt[cc[j] >> BSHIFT], 1);
    }
  }
  __syncthreads();
  for (int b = threadIdx.x; b < NB; b += 256)
    base[b] = cnt[b] ? atomicAdd(&bcnt[b], cnt[b]) : 0;
  __syncthreads();
  #pragma unroll
  for (int j = 0; j < EPB / 256; ++j) {
    long long eid = eb + j * 256 + threadIdx.x;
    if (eid < N_EDGES) {
      int bb = cc[j] >> BSHIFT;
      int pos = bb * BCAP + base[bb] + lr[j];
      ebuf[pos] = ((unsigned)(cc[j] & 255) << 17) | (unsigned)rr[j];
    }
  }
}

// ---------- fused: stage bucket in LDS, degree histogram + dinv + parr + in-bucket sort ----------
__global__ __launch_bounds__(256) void k_degsort(const unsigned* __restrict__ ebuf, const int* __restrict__ bcnt,
                                                 float* __restrict__ dinv, int2* __restrict__ parr,
                                                 int* __restrict__ srow) {
  __shared__ int cnt[256];
  __shared__ int scn[256];
  __shared__ int cur[256];
  __shared__ unsigned eds[BCAP];
  int t = threadIdx.x;
  int b = blockIdx.x;
  int c0 = b << BSHIFT;
  int n = bcnt[b];
  cnt[t] = 0;
  __syncthreads();
  for (int i = t; i < n; i += 256) {
    unsigned w = ebuf[b * BCAP + i];
    eds[i] = w;
    atomicAdd(&cnt[w >> 17], 1);
  }
  __syncthreads();
  int d = cnt[t];
  scn[t] = d;
  __syncthreads();
  for (int off = 1; off < 256; off <<= 1) {
    int u = (t >= off) ? scn[t - off] : 0;
    __syncthreads();
    scn[t] += u;
    __syncthreads();
  }
  int sabs = b * BCAP + scn[t] - d;   // absolute start in (bucket-segmented) srow
  int node = c0 + t;
  if (node < N_NODES) {
    dinv[node] = rsqrtf((float)d + 1.0f);   // +1 = self loop; always > 0
    parr[node] = make_int2(sabs, sabs + d);
  }
  cur[t] = sabs;
  __syncthreads();
  for (int i = t; i < n; i += 256) {
    unsigned w = eds[i];
    int pos = atomicAdd(&cur[w >> 17], 1);
    srow[pos] = (int)(w & 0x1FFFFu);
  }
}

// ---------- MFMA GEMM: Y[n,M] = X[n,K] @ W[K,M], fp16 in, fp32 acc ----------
// Non-FINAL: output row scaled by dinv[row] (folds the source-side GCN norm into storage).
// C/D layout (m89-verified): col = lane&15, row = (lane>>4)*4 + reg.
template<int K, int M, bool FINAL, bool INH>
__global__ __launch_bounds__(256) void k_mfma(const void* __restrict__ X, const float* __restrict__ W,
                                              void* __restrict__ Y, const float* __restrict__ bias,
                                              const float* __restrict__ dscale) {
  constexpr int NN = M / 16;   // n-tiles per wave
  constexpr int KS = K / 32;   // k-steps
  __shared__ char smem[M * K * 2];  // W^T fp16, swizzled

  const int tid = threadIdx.x;
  for (int i = tid; i < K * M / 4; i += 256) {
    int k  = i / (M / 4);
    int mf = (i % (M / 4)) * 4;
    float4 wv = *(const float4*)(W + (size_t)k * M + mf);
    float wa[4] = {wv.x, wv.y, wv.z, wv.w};
    #pragma unroll
    for (int c = 0; c < 4; ++c) {
      int m = mf + c;
      int byte_off = m * (2 * K) + ((((k >> 3) << 4)) ^ ((m & 7) << 4)) + (k & 7) * 2;
      *(_Float16*)(smem + byte_off) = (_Float16)wa[c];
    }
  }
  __syncthreads();

  const int lane = tid & 63;
  const int wv_  = tid >> 6;
  const int rowbase = blockIdx.x * 128 + wv_ * 32;
  const int lr = lane & 15;
  const int kg = lane >> 4;
  const int r0 = rowbase + lr;
  const int r1 = r0 + 16;
  const int rc0 = (r0 < N_NODES) ? r0 : (N_NODES - 1);
  const int rc1 = (r1 < N_NODES) ? r1 : (N_NODES - 1);

  f32x4 acc[2][NN] = {};

  #pragma unroll
  for (int ks = 0; ks < KS; ++ks) {
    const int k0 = ks * 32 + kg * 8;
    f16x8 a0, a1;
    if constexpr (!INH) {
      const float* xr = (const float*)X;
      float4 u0 = *(const float4*)(xr + (size_t)rc0 * K + k0);
      float4 u1 = *(const float4*)(xr + (size_t)rc0 * K + k0 + 4);
      float4 u2 = *(const float4*)(xr + (size_t)rc1 * K + k0);
      float4 u3 = *(const float4*)(xr + (size_t)rc1 * K + k0 + 4);
      a0[0] = (_Float16)u0.x; a0[1] = (_Float16)u0.y; a0[2] = (_Float16)u0.z; a0[3] = (_Float16)u0.w;
      a0[4] = (_Float16)u1.x; a0[5] = (_Float16)u1.y; a0[6] = (_Float16)u1.z; a0[7] = (_Float16)u1.w;
      a1[0] = (_Float16)u2.x; a1[1] = (_Float16)u2.y; a1[2] = (_Float16)u2.z; a1[3] = (_Float16)u2.w;
      a1[4] = (_Float16)u3.x; a1[5] = (_Float16)u3.y; a1[6] = (_Float16)u3.z; a1[7] = (_Float16)u3.w;
    } else {
      const char* xb = (const char*)X;
      a0 = *(const f16x8*)(xb + (size_t)rc0 * (2 * K) + k0 * 2);
      a1 = *(const f16x8*)(xb + (size_t)rc1 * (2 * K) + k0 * 2);
    }
    const int slot = (k0 >> 3) << 4;
    #pragma unroll
    for (int n = 0; n < NN; ++n) {
      const int col = n * 16 + lr;
      f16x8 b = *(const f16x8*)(smem + col * (2 * K) + (slot ^ ((col & 7) << 4)));
      acc[0][n] = __builtin_amdgcn_mfma_f32_16x16x32_f16(a0, b, acc[0][n], 0, 0, 0);
      acc[1][n] = __builtin_amdgcn_mfma_f32_16x16x32_f16(a1, b, acc[1][n], 0, 0, 0);
    }
  }

  #pragma unroll
  for (int m2 = 0; m2 < 2; ++m2) {
    #pragma unroll
    for (int r = 0; r < 4; ++r) {
      const int row = rowbase + m2 * 16 + kg * 4 + r;
      if (row < N_NODES) {
        float ds = FINAL ? 0.f : dscale[row];
        #pragma unroll
        for (int n = 0; n < NN; ++n) {
          const int col = n * 16 + lr;
          float v = acc[m2][n][r];
          if constexpr (FINAL) {
            v += bias[col];
            v = 1.f / (1.f + __expf(-v));
            ((float*)Y)[(size_t)row * M + col] = v;
          } else {
            ((__half*)Y)[(size_t)row * M + col] = __float2half(v * ds);
          }
        }
      }
    }
  }
}

// ---------- pull aggregation: O[c] = relu( dinv[c]*( sum_in H[r] + H[c] ) + b ) ----------
// One wave per node. Lanes 0-31 = even edges, lanes 32-63 = odd edges; each lane owns
// one feature-pair (half2). Per edge: one coalesced 128B row read. Single-level reduce.
__global__ __launch_bounds__(256) void k_agg(const __half* __restrict__ H, __half* __restrict__ O,
                                             const int2* __restrict__ parr, const int* __restrict__ srow,
                                             const float* __restrict__ dinv, const float* __restrict__ bias) {
  int wid  = (blockIdx.x * 256 + threadIdx.x) >> 6;  // node (one wave per node)
  int lane = threadIdx.x & 63;
  if (wid >= N_NODES) return;
  const int hf = lane >> 5;        // edge parity slot
  const int fl = lane & 31;        // feature pair: features 2*fl, 2*fl+1
  const char* Hb = (const char*)H;
  int2 se = parr[wid];
  float ax = 0.f, ay = 0.f;
  #pragma unroll 2
  for (int j = se.x + hf; j < se.y; j += 2) {
    int r = srow[j];
    unsigned h = *(const unsigned*)(Hb + (size_t)r * 128 + fl * 4);
    float2 f = __half22float2(*(__half2*)&h);
    ax += f.x; ay += f.y;
  }
  if (hf == 0) {  // self loop (H[c] pre-scaled by dinv[c])
    unsigned h = *(const unsigned*)(Hb + (size_t)wid * 128 + fl * 4);
    float2 f = __half22float2(*(__half2*)&h);
    ax += f.x; ay += f.y;
  }
  ax += __shfl_xor(ax, 32, 64);
  ay += __shfl_xor(ay, 32, 64);
  if (lane < 32) {
    float di = dinv[wid];
    float2 bv = ((const float2*)bias)[fl];
    __half2 o = __floats2half2_rn(fmaxf(ax * di + bv.x, 0.f), fmaxf(ay * di + bv.y, 0.f));
    *(__half2*)((char*)O + (size_t)wid * 128 + fl * 4) = o;
  }
}

extern "C" void kernel_launch(void* const* d_in, const int* in_sizes, int n_in,
                              void* d_out, int out_size, void* d_ws, size_t ws_size,
                              hipStream_t stream) {
  const float* x   = (const float*)d_in[0];
  const int*   e   = (const int*)d_in[1];
  const float* W1  = (const float*)d_in[2];
  const float* b1  = (const float*)d_in[3];
  const float* W2  = (const float*)d_in[4];
  const float* b2  = (const float*)d_in[5];
  const float* Wfc = (const float*)d_in[6];
  const float* bfc = (const float*)d_in[7];
  float* out = (float*)d_out;

  // workspace layout (bytes) — total ~36.5 MB
  char* ws = (char*)d_ws;
  __half*   hbuf = (__half*)  (ws);             // (N+1)*64 fp16 = 12,800,128 (row N = zero row)
  unsigned* ebuf = (unsigned*)(ws);             // NB*BCAP uint = 9,609,216 (ALIASED on hbuf; dead before gemm1)
  int*      srow = (int*)     (ws + 12800192);  // NB*BCAP i32 = 9,609,216 (bucket-segmented)
  __half*   abuf = (__half*)  (ws + 22409472);  // N*64 fp16 = 12,800,000 (agg outputs)
  float*    dinv = (float*)   (ws + 35209472);  // N f32
  int2*     parr = (int2*)    (ws + 35609472);  // N int2 (start,end)
  int*      flag = (int*)     (ws + 36409472);  // 1 i32
  int*      bcnt = (int*)     (ws + 36409536);  // NB i32

  hipMemsetAsync(bcnt, 0, NB * sizeof(int), stream);
  hipMemsetAsync(ws + (size_t)N_NODES * 128, 0, 128, stream);  // zero row (beyond ebuf's 9.6MB)
  k_detect<<<1, 64, 0, stream>>>((const unsigned int*)e, flag);
  k_bin<<<NBIN_BLK, 256, 0, stream>>>(e, bcnt, ebuf, flag);
  k_degsort<<<NB, 256, 0, stream>>>(ebuf, bcnt, dinv, parr, srow);

  const int gBlocks = (N_NODES + 127) / 128;
  k_mfma<IN_DIM, HID, false, false><<<gBlocks, 256, 0, stream>>>(x, W1, hbuf, nullptr, dinv);
  k_agg<<<N_NODES * 64 / 256, 256, 0, stream>>>(hbuf, abuf, parr, srow, dinv, b1);
  k_mfma<HID, HID, false, true><<<gBlocks, 256, 0, stream>>>(abuf, W2, hbuf, nullptr, dinv);
  k_agg<<<N_NODES * 64 / 256, 256, 0, stream>>>(hbuf, abuf, parr, srow, dinv, b2);
  k_mfma<HID, NCOMM, true, true><<<gBlocks, 256, 0, stream>>>(abuf, Wfc, out, bfc, nullptr);
}

// Round 10
// 188.064 us; speedup vs baseline: 1.1690x; 1.1690x over previous
//
#include <hip/hip_runtime.h>
#include <hip/hip_fp16.h>
#include <math.h>

#define N_NODES 100000
#define N_EDGES 1600000
#define IN_DIM  128
#define HID     64
#define NCOMM   32
#define NB        391   // ceil(100000/256) coarse buckets
#define BSHIFT    8     // 256 nodes per bucket
#define BCAP      6144  // fixed bucket capacity: mean 4096 + 32 sigma (binomial sd=64)
#define EPB       4096  // edges per block in binning kernel
#define NBIN_BLK  391   // ceil(1600000/4096)

typedef _Float16 f16x8 __attribute__((ext_vector_type(8)));
typedef float    f32x4 __attribute__((ext_vector_type(4)));

// ---------- edge dtype detection (int64 vs int32), parallel, deterministic ----------
__global__ void k_detect(const unsigned int* __restrict__ e, int* __restrict__ flag) {
  int lane = threadIdx.x;  // 64 lanes
  unsigned v = 0;
  #pragma unroll
  for (int i = 0; i < 4; ++i) v |= e[2 * (lane * 4 + i) + 1];
  unsigned long long nz = __ballot(v != 0u);
  if (lane == 0) *flag = (nz == 0ull) ? 1 : 0;  // 1 => int64 layout
}

__device__ __forceinline__ int load_idx(const int* e32, long long pos, int is64) {
  if (is64) return (int)(((const long long*)e32)[pos]);
  return e32[pos];
}

// ---------- bin edges into fixed-capacity buckets, packed: bits[0:17)=r, bits[17:25)=c&255 ----------
__global__ __launch_bounds__(256) void k_bin(const int* __restrict__ e, int* __restrict__ bcnt,
                                             unsigned* __restrict__ ebuf, const int* __restrict__ flag) {
  __shared__ int cnt[NB];
  __shared__ int base[NB];
  for (int i = threadIdx.x; i < NB; i += 256) cnt[i] = 0;
  __syncthreads();
  int is64 = *flag;
  long long eb = (long long)blockIdx.x * EPB;
  int rr[EPB / 256], cc[EPB / 256], lr[EPB / 256];
  #pragma unroll
  for (int j = 0; j < EPB / 256; ++j) {
    long long eid = eb + j * 256 + threadIdx.x;
    if (eid < N_EDGES) {
      rr[j] = load_idx(e, eid, is64);
      cc[j] = load_idx(e, (long long)N_EDGES + eid, is64);
      lr[j] = atomicAdd(&cnt[cc[j] >> BSHIFT], 1);
    }
  }
  __syncthreads();
  for (int b = threadIdx.x; b < NB; b += 256)
    base[b] = cnt[b] ? atomicAdd(&bcnt[b], cnt[b]) : 0;
  __syncthreads();
  #pragma unroll
  for (int j = 0; j < EPB / 256; ++j) {
    long long eid = eb + j * 256 + threadIdx.x;
    if (eid < N_EDGES) {
      int bb = cc[j] >> BSHIFT;
      int pos = bb * BCAP + base[bb] + lr[j];
      ebuf[pos] = ((unsigned)(cc[j] & 255) << 17) | (unsigned)rr[j];
    }
  }
}

// ---------- fused: stage bucket in LDS, degree histogram + dinv + parr + in-bucket sort ----------
__global__ __launch_bounds__(256) void k_degsort(const unsigned* __restrict__ ebuf, const int* __restrict__ bcnt,
                                                 float* __restrict__ dinv, int2* __restrict__ parr,
                                                 int* __restrict__ srow) {
  __shared__ int cnt[256];
  __shared__ int scn[256];
  __shared__ int cur[256];
  __shared__ unsigned eds[BCAP];
  int t = threadIdx.x;
  int b = blockIdx.x;
  int c0 = b << BSHIFT;
  int n = bcnt[b];
  cnt[t] = 0;
  __syncthreads();
  for (int i = t; i < n; i += 256) {
    unsigned w = ebuf[b * BCAP + i];
    eds[i] = w;
    atomicAdd(&cnt[w >> 17], 1);
  }
  __syncthreads();
  int d = cnt[t];
  scn[t] = d;
  __syncthreads();
  for (int off = 1; off < 256; off <<= 1) {
    int u = (t >= off) ? scn[t - off] : 0;
    __syncthreads();
    scn[t] += u;
    __syncthreads();
  }
  int sabs = b * BCAP + scn[t] - d;   // absolute start in (bucket-segmented) srow
  int node = c0 + t;
  if (node < N_NODES) {
    dinv[node] = rsqrtf((float)d + 1.0f);   // +1 = self loop; always > 0
    parr[node] = make_int2(sabs, sabs + d);
  }
  cur[t] = sabs;
  __syncthreads();
  for (int i = t; i < n; i += 256) {
    unsigned w = eds[i];
    int pos = atomicAdd(&cur[w >> 17], 1);
    srow[pos] = (int)(w & 0x1FFFFu);
  }
}

// ---------- MFMA GEMM: Y[n,M] = X[n,K] @ W[K,M], fp16 in, fp32 acc ----------
// Non-FINAL: output row scaled by dinv[row] (folds the source-side GCN norm into storage).
// C/D layout (m89-verified): col = lane&15, row = (lane>>4)*4 + reg.
template<int K, int M, bool FINAL, bool INH>
__global__ __launch_bounds__(256) void k_mfma(const void* __restrict__ X, const float* __restrict__ W,
                                              void* __restrict__ Y, const float* __restrict__ bias,
                                              const float* __restrict__ dscale) {
  constexpr int NN = M / 16;   // n-tiles per wave
  constexpr int KS = K / 32;   // k-steps
  __shared__ char smem[M * K * 2];  // W^T fp16, swizzled

  const int tid = threadIdx.x;
  for (int i = tid; i < K * M / 4; i += 256) {
    int k  = i / (M / 4);
    int mf = (i % (M / 4)) * 4;
    float4 wv = *(const float4*)(W + (size_t)k * M + mf);
    float wa[4] = {wv.x, wv.y, wv.z, wv.w};
    #pragma unroll
    for (int c = 0; c < 4; ++c) {
      int m = mf + c;
      int byte_off = m * (2 * K) + ((((k >> 3) << 4)) ^ ((m & 7) << 4)) + (k & 7) * 2;
      *(_Float16*)(smem + byte_off) = (_Float16)wa[c];
    }
  }
  __syncthreads();

  const int lane = tid & 63;
  const int wv_  = tid >> 6;
  const int rowbase = blockIdx.x * 128 + wv_ * 32;
  const int lr = lane & 15;
  const int kg = lane >> 4;
  const int r0 = rowbase + lr;
  const int r1 = r0 + 16;
  const int rc0 = (r0 < N_NODES) ? r0 : (N_NODES - 1);
  const int rc1 = (r1 < N_NODES) ? r1 : (N_NODES - 1);

  f32x4 acc[2][NN] = {};

  #pragma unroll
  for (int ks = 0; ks < KS; ++ks) {
    const int k0 = ks * 32 + kg * 8;
    f16x8 a0, a1;
    if constexpr (!INH) {
      const float* xr = (const float*)X;
      float4 u0 = *(const float4*)(xr + (size_t)rc0 * K + k0);
      float4 u1 = *(const float4*)(xr + (size_t)rc0 * K + k0 + 4);
      float4 u2 = *(const float4*)(xr + (size_t)rc1 * K + k0);
      float4 u3 = *(const float4*)(xr + (size_t)rc1 * K + k0 + 4);
      a0[0] = (_Float16)u0.x; a0[1] = (_Float16)u0.y; a0[2] = (_Float16)u0.z; a0[3] = (_Float16)u0.w;
      a0[4] = (_Float16)u1.x; a0[5] = (_Float16)u1.y; a0[6] = (_Float16)u1.z; a0[7] = (_Float16)u1.w;
      a1[0] = (_Float16)u2.x; a1[1] = (_Float16)u2.y; a1[2] = (_Float16)u2.z; a1[3] = (_Float16)u2.w;
      a1[4] = (_Float16)u3.x; a1[5] = (_Float16)u3.y; a1[6] = (_Float16)u3.z; a1[7] = (_Float16)u3.w;
    } else {
      const char* xb = (const char*)X;
      a0 = *(const f16x8*)(xb + (size_t)rc0 * (2 * K) + k0 * 2);
      a1 = *(const f16x8*)(xb + (size_t)rc1 * (2 * K) + k0 * 2);
    }
    const int slot = (k0 >> 3) << 4;
    #pragma unroll
    for (int n = 0; n < NN; ++n) {
      const int col = n * 16 + lr;
      f16x8 b = *(const f16x8*)(smem + col * (2 * K) + (slot ^ ((col & 7) << 4)));
      acc[0][n] = __builtin_amdgcn_mfma_f32_16x16x32_f16(a0, b, acc[0][n], 0, 0, 0);
      acc[1][n] = __builtin_amdgcn_mfma_f32_16x16x32_f16(a1, b, acc[1][n], 0, 0, 0);
    }
  }

  #pragma unroll
  for (int m2 = 0; m2 < 2; ++m2) {
    #pragma unroll
    for (int r = 0; r < 4; ++r) {
      const int row = rowbase + m2 * 16 + kg * 4 + r;
      if (row < N_NODES) {
        float ds = FINAL ? 0.f : dscale[row];
        #pragma unroll
        for (int n = 0; n < NN; ++n) {
          const int col = n * 16 + lr;
          float v = acc[m2][n][r];
          if constexpr (FINAL) {
            v += bias[col];
            v = 1.f / (1.f + __expf(-v));
            ((float*)Y)[(size_t)row * M + col] = v;
          } else {
            ((__half*)Y)[(size_t)row * M + col] = __float2half(v * ds);
          }
        }
      }
    }
  }
}

// ---------- pull aggregation: O[c] = relu( dinv[c]*( sum_in H[r] + H[c] ) + b ) ----------
// Round-8 proven structure: 8 edge slots x 8-lane feature octets, 16B loads, unroll 2
// -> 16 independent row-gathers in flight per wave (MLP-bound regime).
// H rows pre-scaled by dinv[r]; row N_NODES is a zero row for tail slots.
__device__ __forceinline__ void addrow(float* acc, uint4 h) {
  __half2 p0 = *(__half2*)&h.x;
  __half2 p1 = *(__half2*)&h.y;
  __half2 p2 = *(__half2*)&h.z;
  __half2 p3 = *(__half2*)&h.w;
  float2 f0 = __half22float2(p0);
  float2 f1 = __half22float2(p1);
  float2 f2 = __half22float2(p2);
  float2 f3 = __half22float2(p3);
  acc[0] += f0.x; acc[1] += f0.y;
  acc[2] += f1.x; acc[3] += f1.y;
  acc[4] += f2.x; acc[5] += f2.y;
  acc[6] += f3.x; acc[7] += f3.y;
}

__global__ __launch_bounds__(256) void k_agg(const __half* __restrict__ H, __half* __restrict__ O,
                                             const int2* __restrict__ parr, const int* __restrict__ srow,
                                             const float* __restrict__ dinv, const float* __restrict__ bias) {
  int wid  = (blockIdx.x * 256 + threadIdx.x) >> 6;  // node (one wave per node)
  int lane = threadIdx.x & 63;
  if (wid >= N_NODES) return;
  const int q  = lane >> 3;   // edge slot 0..7
  const int fl = lane & 7;    // feature octet: features 8*fl .. 8*fl+7 (16 B)
  const char* Hb = (const char*)H;
  int2 se = parr[wid];
  int s = se.x, e = se.y;
  float acc[8] = {0.f, 0.f, 0.f, 0.f, 0.f, 0.f, 0.f, 0.f};
  for (int j = s; j < e; j += 16) {
    int i0 = j + q;
    int i1 = j + 8 + q;
    int r0 = srow[i0];               // srow segment has >=60B pad; garbage select-replaced
    int r1 = srow[i1];
    r0 = (i0 < e) ? r0 : N_NODES;    // zero row
    r1 = (i1 < e) ? r1 : N_NODES;
    uint4 h0 = *(const uint4*)(Hb + (size_t)((unsigned)r0 * 128u + (unsigned)fl * 16u));
    uint4 h1 = *(const uint4*)(Hb + (size_t)((unsigned)r1 * 128u + (unsigned)fl * 16u));
    addrow(acc, h0);
    addrow(acc, h1);
  }
  if (q == 0) {  // self loop (H[c] pre-scaled by dinv[c])
    uint4 hb = *(const uint4*)(Hb + (size_t)((unsigned)wid * 128u + (unsigned)fl * 16u));
    addrow(acc, hb);
  }
  // merge the 8 edge slots
  #pragma unroll
  for (int m = 8; m < 64; m <<= 1) {
    #pragma unroll
    for (int i = 0; i < 8; ++i) acc[i] += __shfl_xor(acc[i], m, 64);
  }
  if (lane < 8) {
    float di = dinv[wid];
    float4 ba = ((const float4*)bias)[2 * fl + 0];
    float4 bb = ((const float4*)bias)[2 * fl + 1];
    __half2 o0 = __floats2half2_rn(fmaxf(acc[0] * di + ba.x, 0.f), fmaxf(acc[1] * di + ba.y, 0.f));
    __half2 o1 = __floats2half2_rn(fmaxf(acc[2] * di + ba.z, 0.f), fmaxf(acc[3] * di + ba.w, 0.f));
    __half2 o2 = __floats2half2_rn(fmaxf(acc[4] * di + bb.x, 0.f), fmaxf(acc[5] * di + bb.y, 0.f));
    __half2 o3 = __floats2half2_rn(fmaxf(acc[6] * di + bb.z, 0.f), fmaxf(acc[7] * di + bb.w, 0.f));
    uint4 pv;
    pv.x = *(unsigned*)&o0;
    pv.y = *(unsigned*)&o1;
    pv.z = *(unsigned*)&o2;
    pv.w = *(unsigned*)&o3;
    *(uint4*)((char*)O + (size_t)wid * (HID * 2) + fl * 16) = pv;
  }
}

extern "C" void kernel_launch(void* const* d_in, const int* in_sizes, int n_in,
                              void* d_out, int out_size, void* d_ws, size_t ws_size,
                              hipStream_t stream) {
  const float* x   = (const float*)d_in[0];
  const int*   e   = (const int*)d_in[1];
  const float* W1  = (const float*)d_in[2];
  const float* b1  = (const float*)d_in[3];
  const float* W2  = (const float*)d_in[4];
  const float* b2  = (const float*)d_in[5];
  const float* Wfc = (const float*)d_in[6];
  const float* bfc = (const float*)d_in[7];
  float* out = (float*)d_out;

  // workspace layout (bytes) — total ~36.5 MB
  char* ws = (char*)d_ws;
  __half*   hbuf = (__half*)  (ws);             // (N+1)*64 fp16 = 12,800,128 (row N = zero row)
  unsigned* ebuf = (unsigned*)(ws);             // NB*BCAP uint = 9,609,216 (ALIASED on hbuf; dead before gemm1)
  int*      srow = (int*)     (ws + 12800192);  // NB*BCAP i32 = 9,609,216 (bucket-segmented, 64B pad after)
  __half*   abuf = (__half*)  (ws + 22409472);  // N*64 fp16 = 12,800,000 (agg outputs)
  float*    dinv = (float*)   (ws + 35209472);  // N f32
  int2*     parr = (int2*)    (ws + 35609472);  // N int2 (start,end)
  int*      flag = (int*)     (ws + 36409472);  // 1 i32
  int*      bcnt = (int*)     (ws + 36409536);  // NB i32

  hipMemsetAsync(bcnt, 0, NB * sizeof(int), stream);
  hipMemsetAsync(ws + (size_t)N_NODES * 128, 0, 128, stream);  // zero row (beyond ebuf's 9.6MB)
  k_detect<<<1, 64, 0, stream>>>((const unsigned int*)e, flag);
  k_bin<<<NBIN_BLK, 256, 0, stream>>>(e, bcnt, ebuf, flag);
  k_degsort<<<NB, 256, 0, stream>>>(ebuf, bcnt, dinv, parr, srow);

  const int gBlocks = (N_NODES + 127) / 128;
  k_mfma<IN_DIM, HID, false, false><<<gBlocks, 256, 0, stream>>>(x, W1, hbuf, nullptr, dinv);
  k_agg<<<N_NODES * 64 / 256, 256, 0, stream>>>(hbuf, abuf, parr, srow, dinv, b1);
  k_mfma<HID, HID, false, true><<<gBlocks, 256, 0, stream>>>(abuf, W2, hbuf, nullptr, dinv);
  k_agg<<<N_NODES * 64 / 256, 256, 0, stream>>>(hbuf, abuf, parr, srow, dinv, b2);
  k_mfma<HID, NCOMM, true, true><<<gBlocks, 256, 0, stream>>>(abuf, Wfc, out, bfc, nullptr);
}

// Round 11
// 186.858 us; speedup vs baseline: 1.1765x; 1.0065x over previous
//
#include <hip/hip_runtime.h>
#include <hip/hip_fp16.h>
#include <math.h>

#define N_NODES 100000
#define N_EDGES 1600000
#define IN_DIM  128
#define HID     64
#define NCOMM   32
#define NB        391   // ceil(100000/256) coarse buckets
#define BSHIFT    8     // 256 nodes per bucket
#define BCAP      6144  // fixed bucket capacity: mean 4096 + 32 sigma (binomial sd=64)
#define EPB       2048  // edges per block in binning kernel (782 blocks = 3/CU)
#define NBIN_BLK  782   // ceil(1600000/2048)

typedef _Float16 f16x8 __attribute__((ext_vector_type(8)));
typedef float    f32x4 __attribute__((ext_vector_type(4)));

__device__ __forceinline__ int load_idx(const int* e32, long long pos, int is64) {
  if (is64) return (int)(((const long long*)e32)[pos]);
  return e32[pos];
}

// ---------- init: zero bcnt + zero gather-row (replaces 2 memsets + detect launch) ----------
__global__ __launch_bounds__(512) void k_init(int* __restrict__ bcnt, int* __restrict__ zrow) {
  int t = threadIdx.x;
  if (t < NB) bcnt[t] = 0;
  if (t >= 480) zrow[t - 480] = 0;   // 32 ints = 128 B zero row
}

// ---------- bin edges into fixed-capacity buckets, packed: bits[0:17)=r, bits[17:25)=c&255 ----------
// Self-detects int64-vs-int32 edge layout per block (high words of first 256 entries).
__global__ __launch_bounds__(256) void k_bin(const int* __restrict__ e, int* __restrict__ bcnt,
                                             unsigned* __restrict__ ebuf) {
  __shared__ int cnt[NB];
  __shared__ int base[NB];
  __shared__ int s_hi;
  if (threadIdx.x == 0) s_hi = 0;
  for (int i = threadIdx.x; i < NB; i += 256) cnt[i] = 0;
  __syncthreads();
  if (((const unsigned*)e)[2 * threadIdx.x + 1] != 0u) atomicOr(&s_hi, 1);
  __syncthreads();
  const int is64 = (s_hi == 0);  // all-zero high words => int64 layout
  long long eb = (long long)blockIdx.x * EPB;
  int rr[EPB / 256], cc[EPB / 256], lr[EPB / 256];
  #pragma unroll
  for (int j = 0; j < EPB / 256; ++j) {
    long long eid = eb + j * 256 + threadIdx.x;
    if (eid < N_EDGES) {
      rr[j] = load_idx(e, eid, is64);
      cc[j] = load_idx(e, (long long)N_EDGES + eid, is64);
      lr[j] = atomicAdd(&cnt[cc[j] >> BSHIFT], 1);
    }
  }
  __syncthreads();
  for (int b = threadIdx.x; b < NB; b += 256)
    base[b] = cnt[b] ? atomicAdd(&bcnt[b], cnt[b]) : 0;
  __syncthreads();
  #pragma unroll
  for (int j = 0; j < EPB / 256; ++j) {
    long long eid = eb + j * 256 + threadIdx.x;
    if (eid < N_EDGES) {
      int bb = cc[j] >> BSHIFT;
      int pos = bb * BCAP + base[bb] + lr[j];
      ebuf[pos] = ((unsigned)(cc[j] & 255) << 17) | (unsigned)rr[j];
    }
  }
}

// ---------- fused: stage bucket in LDS, degree histogram + dinv + parr + in-bucket sort ----------
// 512 threads: halves staging/scatter time per block (grid fixed at NB by cursor exclusivity).
__global__ __launch_bounds__(512) void k_degsort(const unsigned* __restrict__ ebuf, const int* __restrict__ bcnt,
                                                 float* __restrict__ dinv, int2* __restrict__ parr,
                                                 int* __restrict__ srow) {
  __shared__ int cnt[256];
  __shared__ int scn[256];
  __shared__ int cur[256];
  __shared__ unsigned eds[BCAP];
  int t = threadIdx.x;
  int b = blockIdx.x;
  int c0 = b << BSHIFT;
  int n = bcnt[b];
  if (t < 256) cnt[t] = 0;
  __syncthreads();
  for (int i = t; i < n; i += 512) {
    unsigned w = ebuf[b * BCAP + i];
    eds[i] = w;
    atomicAdd(&cnt[w >> 17], 1);
  }
  __syncthreads();
  int d = (t < 256) ? cnt[t] : 0;
  if (t < 256) scn[t] = d;
  __syncthreads();
  for (int off = 1; off < 256; off <<= 1) {
    int u = (t >= off && t < 256) ? scn[t - off] : 0;
    __syncthreads();
    if (t < 256) scn[t] += u;
    __syncthreads();
  }
  if (t < 256) {
    int sabs = b * BCAP + scn[t] - d;   // absolute start in (bucket-segmented) srow
    int node = c0 + t;
    if (node < N_NODES) {
      dinv[node] = rsqrtf((float)d + 1.0f);   // +1 = self loop; always > 0
      parr[node] = make_int2(sabs, sabs + d);
    }
    cur[t] = sabs;
  }
  __syncthreads();
  for (int i = t; i < n; i += 512) {
    unsigned w = eds[i];
    int pos = atomicAdd(&cur[w >> 17], 1);
    srow[pos] = (int)(w & 0x1FFFFu);
  }
}

// ---------- MFMA GEMM: Y[n,M] = X[n,K] @ W[K,M], fp16 in, fp32 acc ----------
// Non-FINAL: output row scaled by dinv[row] (folds the source-side GCN norm into storage).
// C/D layout (m89-verified): col = lane&15, row = (lane>>4)*4 + reg.
template<int K, int M, bool FINAL, bool INH>
__global__ __launch_bounds__(256) void k_mfma(const void* __restrict__ X, const float* __restrict__ W,
                                              void* __restrict__ Y, const float* __restrict__ bias,
                                              const float* __restrict__ dscale) {
  constexpr int NN = M / 16;   // n-tiles per wave
  constexpr int KS = K / 32;   // k-steps
  __shared__ char smem[M * K * 2];  // W^T fp16, swizzled

  const int tid = threadIdx.x;
  for (int i = tid; i < K * M / 4; i += 256) {
    int k  = i / (M / 4);
    int mf = (i % (M / 4)) * 4;
    float4 wv = *(const float4*)(W + (size_t)k * M + mf);
    float wa[4] = {wv.x, wv.y, wv.z, wv.w};
    #pragma unroll
    for (int c = 0; c < 4; ++c) {
      int m = mf + c;
      int byte_off = m * (2 * K) + ((((k >> 3) << 4)) ^ ((m & 7) << 4)) + (k & 7) * 2;
      *(_Float16*)(smem + byte_off) = (_Float16)wa[c];
    }
  }
  __syncthreads();

  const int lane = tid & 63;
  const int wv_  = tid >> 6;
  const int rowbase = blockIdx.x * 128 + wv_ * 32;
  const int lr = lane & 15;
  const int kg = lane >> 4;
  const int r0 = rowbase + lr;
  const int r1 = r0 + 16;
  const int rc0 = (r0 < N_NODES) ? r0 : (N_NODES - 1);
  const int rc1 = (r1 < N_NODES) ? r1 : (N_NODES - 1);

  f32x4 acc[2][NN] = {};

  #pragma unroll
  for (int ks = 0; ks < KS; ++ks) {
    const int k0 = ks * 32 + kg * 8;
    f16x8 a0, a1;
    if constexpr (!INH) {
      const float* xr = (const float*)X;
      float4 u0 = *(const float4*)(xr + (size_t)rc0 * K + k0);
      float4 u1 = *(const float4*)(xr + (size_t)rc0 * K + k0 + 4);
      float4 u2 = *(const float4*)(xr + (size_t)rc1 * K + k0);
      float4 u3 = *(const float4*)(xr + (size_t)rc1 * K + k0 + 4);
      a0[0] = (_Float16)u0.x; a0[1] = (_Float16)u0.y; a0[2] = (_Float16)u0.z; a0[3] = (_Float16)u0.w;
      a0[4] = (_Float16)u1.x; a0[5] = (_Float16)u1.y; a0[6] = (_Float16)u1.z; a0[7] = (_Float16)u1.w;
      a1[0] = (_Float16)u2.x; a1[1] = (_Float16)u2.y; a1[2] = (_Float16)u2.z; a1[3] = (_Float16)u2.w;
      a1[4] = (_Float16)u3.x; a1[5] = (_Float16)u3.y; a1[6] = (_Float16)u3.z; a1[7] = (_Float16)u3.w;
    } else {
      const char* xb = (const char*)X;
      a0 = *(const f16x8*)(xb + (size_t)rc0 * (2 * K) + k0 * 2);
      a1 = *(const f16x8*)(xb + (size_t)rc1 * (2 * K) + k0 * 2);
    }
    const int slot = (k0 >> 3) << 4;
    #pragma unroll
    for (int n = 0; n < NN; ++n) {
      const int col = n * 16 + lr;
      f16x8 b = *(const f16x8*)(smem + col * (2 * K) + (slot ^ ((col & 7) << 4)));
      acc[0][n] = __builtin_amdgcn_mfma_f32_16x16x32_f16(a0, b, acc[0][n], 0, 0, 0);
      acc[1][n] = __builtin_amdgcn_mfma_f32_16x16x32_f16(a1, b, acc[1][n], 0, 0, 0);
    }
  }

  #pragma unroll
  for (int m2 = 0; m2 < 2; ++m2) {
    #pragma unroll
    for (int r = 0; r < 4; ++r) {
      const int row = rowbase + m2 * 16 + kg * 4 + r;
      if (row < N_NODES) {
        float ds = FINAL ? 0.f : dscale[row];
        #pragma unroll
        for (int n = 0; n < NN; ++n) {
          const int col = n * 16 + lr;
          float v = acc[m2][n][r];
          if constexpr (FINAL) {
            v += bias[col];
            v = 1.f / (1.f + __expf(-v));
            ((float*)Y)[(size_t)row * M + col] = v;
          } else {
            ((__half*)Y)[(size_t)row * M + col] = __float2half(v * ds);
          }
        }
      }
    }
  }
}

// ---------- pull aggregation: O[c] = relu( dinv[c]*( sum_in H[r] + H[c] ) + b ) ----------
// Proven structure (r8/r10): 8 edge slots x 8-lane feature octets, 16B loads, unroll 2
// -> 16 independent row-gathers in flight per wave. H rows pre-scaled by dinv[r];
// row N_NODES is a zero row for tail slots.
__device__ __forceinline__ void addrow(float* acc, uint4 h) {
  __half2 p0 = *(__half2*)&h.x;
  __half2 p1 = *(__half2*)&h.y;
  __half2 p2 = *(__half2*)&h.z;
  __half2 p3 = *(__half2*)&h.w;
  float2 f0 = __half22float2(p0);
  float2 f1 = __half22float2(p1);
  float2 f2 = __half22float2(p2);
  float2 f3 = __half22float2(p3);
  acc[0] += f0.x; acc[1] += f0.y;
  acc[2] += f1.x; acc[3] += f1.y;
  acc[4] += f2.x; acc[5] += f2.y;
  acc[6] += f3.x; acc[7] += f3.y;
}

__global__ __launch_bounds__(256) void k_agg(const __half* __restrict__ H, __half* __restrict__ O,
                                             const int2* __restrict__ parr, const int* __restrict__ srow,
                                             const float* __restrict__ dinv, const float* __restrict__ bias) {
  int wid  = (blockIdx.x * 256 + threadIdx.x) >> 6;  // node (one wave per node)
  int lane = threadIdx.x & 63;
  if (wid >= N_NODES) return;
  const int q  = lane >> 3;   // edge slot 0..7
  const int fl = lane & 7;    // feature octet: features 8*fl .. 8*fl+7 (16 B)
  const char* Hb = (const char*)H;
  int2 se = parr[wid];
  int s = se.x, e = se.y;
  float acc[8] = {0.f, 0.f, 0.f, 0.f, 0.f, 0.f, 0.f, 0.f};
  for (int j = s; j < e; j += 16) {
    int i0 = j + q;
    int i1 = j + 8 + q;
    int r0 = srow[i0];               // srow segment has pad; garbage select-replaced
    int r1 = srow[i1];
    r0 = (i0 < e) ? r0 : N_NODES;    // zero row
    r1 = (i1 < e) ? r1 : N_NODES;
    uint4 h0 = *(const uint4*)(Hb + (size_t)((unsigned)r0 * 128u + (unsigned)fl * 16u));
    uint4 h1 = *(const uint4*)(Hb + (size_t)((unsigned)r1 * 128u + (unsigned)fl * 16u));
    addrow(acc, h0);
    addrow(acc, h1);
  }
  if (q == 0) {  // self loop (H[c] pre-scaled by dinv[c])
    uint4 hb = *(const uint4*)(Hb + (size_t)((unsigned)wid * 128u + (unsigned)fl * 16u));
    addrow(acc, hb);
  }
  // merge the 8 edge slots
  #pragma unroll
  for (int m = 8; m < 64; m <<= 1) {
    #pragma unroll
    for (int i = 0; i < 8; ++i) acc[i] += __shfl_xor(acc[i], m, 64);
  }
  if (lane < 8) {
    float di = dinv[wid];
    float4 ba = ((const float4*)bias)[2 * fl + 0];
    float4 bb = ((const float4*)bias)[2 * fl + 1];
    __half2 o0 = __floats2half2_rn(fmaxf(acc[0] * di + ba.x, 0.f), fmaxf(acc[1] * di + ba.y, 0.f));
    __half2 o1 = __floats2half2_rn(fmaxf(acc[2] * di + ba.z, 0.f), fmaxf(acc[3] * di + ba.w, 0.f));
    __half2 o2 = __floats2half2_rn(fmaxf(acc[4] * di + bb.x, 0.f), fmaxf(acc[5] * di + bb.y, 0.f));
    __half2 o3 = __floats2half2_rn(fmaxf(acc[6] * di + bb.z, 0.f), fmaxf(acc[7] * di + bb.w, 0.f));
    uint4 pv;
    pv.x = *(unsigned*)&o0;
    pv.y = *(unsigned*)&o1;
    pv.z = *(unsigned*)&o2;
    pv.w = *(unsigned*)&o3;
    *(uint4*)((char*)O + (size_t)wid * (HID * 2) + fl * 16) = pv;
  }
}

extern "C" void kernel_launch(void* const* d_in, const int* in_sizes, int n_in,
                              void* d_out, int out_size, void* d_ws, size_t ws_size,
                              hipStream_t stream) {
  const float* x   = (const float*)d_in[0];
  const int*   e   = (const int*)d_in[1];
  const float* W1  = (const float*)d_in[2];
  const float* b1  = (const float*)d_in[3];
  const float* W2  = (const float*)d_in[4];
  const float* b2  = (const float*)d_in[5];
  const float* Wfc = (const float*)d_in[6];
  const float* bfc = (const float*)d_in[7];
  float* out = (float*)d_out;

  // workspace layout (bytes) — total ~36.5 MB
  char* ws = (char*)d_ws;
  __half*   hbuf = (__half*)  (ws);             // (N+1)*64 fp16 = 12,800,128 (row N = zero row)
  unsigned* ebuf = (unsigned*)(ws);             // NB*BCAP uint = 9,609,216 (ALIASED on hbuf; dead before gemm1)
  int*      srow = (int*)     (ws + 12800192);  // NB*BCAP i32 = 9,609,216 (bucket-segmented, 64B pad after)
  __half*   abuf = (__half*)  (ws + 22409472);  // N*64 fp16 = 12,800,000 (agg outputs)
  float*    dinv = (float*)   (ws + 35209472);  // N f32
  int2*     parr = (int2*)    (ws + 35609472);  // N int2 (start,end)
  int*      bcnt = (int*)     (ws + 36409536);  // NB i32

  k_init<<<1, 512, 0, stream>>>(bcnt, (int*)(ws + (size_t)N_NODES * 128));
  k_bin<<<NBIN_BLK, 256, 0, stream>>>(e, bcnt, ebuf);
  k_degsort<<<NB, 512, 0, stream>>>(ebuf, bcnt, dinv, parr, srow);

  const int gBlocks = (N_NODES + 127) / 128;
  k_mfma<IN_DIM, HID, false, false><<<gBlocks, 256, 0, stream>>>(x, W1, hbuf, nullptr, dinv);
  k_agg<<<N_NODES * 64 / 256, 256, 0, stream>>>(hbuf, abuf, parr, srow, dinv, b1);
  k_mfma<HID, HID, false, true><<<gBlocks, 256, 0, stream>>>(abuf, W2, hbuf, nullptr, dinv);
  k_agg<<<N_NODES * 64 / 256, 256, 0, stream>>>(hbuf, abuf, parr, srow, dinv, b2);
  k_mfma<HID, NCOMM, true, true><<<gBlocks, 256, 0, stream>>>(abuf, Wfc, out, bfc, nullptr);
}